// Round 1
// baseline (652.578 us; speedup 1.0000x reference)
//
#include <hip/hip_runtime.h>
#include <hip/hip_bf16.h>

// SeqExperts: 64 experts, 128 tokens each, d_model=1024, d_hidden=4096.
// out[e*128+m] = relu(x_e @ W1[e]^T) @ W2[e]^T
// Two grouped-GEMM passes, bf16 MFMA, weights converted fp32->bf16 at LDS-stage time.

typedef __attribute__((ext_vector_type(8))) short bf16x8;   // 8 bf16 = 4 VGPRs (MFMA A/B frag)
typedef __attribute__((ext_vector_type(4))) float f32x4;    // MFMA C/D frag

#define N_EXPERTS 64
#define DM 1024
#define DH 4096
#define TOKS 128

// RNE fp32 -> bf16 (no NaN handling needed: inputs are finite normals)
__device__ __forceinline__ unsigned short f2bf(float f) {
    union { float f; unsigned u; } v; v.f = f;
    unsigned r = v.u + 0x7FFFu + ((v.u >> 16) & 1u);
    return (unsigned short)(r >> 16);
}

// C[128 x N] = A[128 x K] * B[N x K]^T  for expert e = blockIdx / (N/128)
// A: fp32 (pass1 inputs) or bf16 (pass2 h), row-major lda=K
// B: fp32 weights, row-major [N][K] (so B^T layout: K contiguous)
// C: pass1 -> bf16 + relu (h), pass2 -> fp32 (out). ldc=N.
template<int N, int K, bool A_BF16, bool RELU_OUT_BF16>
__global__ __launch_bounds__(256, 2)
void moe_gemm(const void* __restrict__ Ap, const float* __restrict__ Bp,
              void* __restrict__ Cp)
{
    constexpr int BK = 32;          // K elements per LDS tile
    constexpr int NT = K / BK;      // K-steps
    constexpr int NTILES = N / 128; // N tiles per expert

    __shared__ unsigned short sA[2][128][BK];  // bf16 tiles, [buf][row][k] (8 KiB each)
    __shared__ unsigned short sB[2][128][BK];

    const int tid = threadIdx.x;
    const int bid = blockIdx.x;
    const int e   = bid / NTILES;
    const int nt  = bid % NTILES;

    const int lane = tid & 63;
    const int w    = tid >> 6;       // wave 0..3
    const int wr   = w >> 1;         // wave row (0..1) -> 64 rows
    const int wc   = w & 1;          // wave col (0..1) -> 64 cols
    const int lrow = lane & 15;      // fragment row/col index
    const int kq   = lane >> 4;      // k-quarter 0..3 (8 bf16 each)

    const float* Bbase = Bp + (size_t)e * N * K + (size_t)nt * 128 * K;

    const float*          Af = nullptr;
    const unsigned short* Ah = nullptr;
    if constexpr (A_BF16) Ah = (const unsigned short*)Ap + (size_t)e * TOKS * K;
    else                  Af = (const float*)Ap + (size_t)e * TOKS * K;

    // staging decomposition
    const int srow = tid >> 3;   // 0..31 (fp32 tiles: row = srow + j*32, 4 float4/row-group)
    const int sc4  = tid & 7;    // float4 column within row (cols sc4*4 .. +3)
    const int hrow = tid >> 2;   // 0..63 (bf16 A tile: row = hrow + j*64)
    const int hc8  = tid & 3;    // 8-bf16 chunk within row

    float4 bReg[4];
    float4 aRegF[4];
    uint4  aRegH[2];

    f32x4 acc[4][4];
    #pragma unroll
    for (int i = 0; i < 4; ++i)
        #pragma unroll
        for (int n = 0; n < 4; ++n)
            #pragma unroll
            for (int q = 0; q < 4; ++q) acc[i][n][q] = 0.f;

    auto LOAD = [&](int t) {
        const int k0 = t * BK;
        #pragma unroll
        for (int j = 0; j < 4; ++j)
            bReg[j] = *(const float4*)(Bbase + (size_t)(srow + j * 32) * K + k0 + sc4 * 4);
        if constexpr (A_BF16) {
            #pragma unroll
            for (int j = 0; j < 2; ++j)
                aRegH[j] = *(const uint4*)(Ah + (size_t)(hrow + j * 64) * K + k0 + hc8 * 8);
        } else {
            #pragma unroll
            for (int j = 0; j < 4; ++j)
                aRegF[j] = *(const float4*)(Af + (size_t)(srow + j * 32) * K + k0 + sc4 * 4);
        }
    };

    auto WRITE = [&](int buf) {
        #pragma unroll
        for (int j = 0; j < 4; ++j) {
            ushort4 p;
            p.x = f2bf(bReg[j].x); p.y = f2bf(bReg[j].y);
            p.z = f2bf(bReg[j].z); p.w = f2bf(bReg[j].w);
            *(ushort4*)&sB[buf][srow + j * 32][sc4 * 4] = p;
        }
        if constexpr (A_BF16) {
            #pragma unroll
            for (int j = 0; j < 2; ++j)
                *(uint4*)&sA[buf][hrow + j * 64][hc8 * 8] = aRegH[j];
        } else {
            #pragma unroll
            for (int j = 0; j < 4; ++j) {
                ushort4 p;
                p.x = f2bf(aRegF[j].x); p.y = f2bf(aRegF[j].y);
                p.z = f2bf(aRegF[j].z); p.w = f2bf(aRegF[j].w);
                *(ushort4*)&sA[buf][srow + j * 32][sc4 * 4] = p;
            }
        }
    };

    LOAD(0);
    WRITE(0);
    __syncthreads();

    #pragma unroll 2
    for (int t = 0; t < NT; ++t) {
        const int buf = t & 1;
        if (t + 1 < NT) LOAD(t + 1);       // issue next tile's global loads early

        bf16x8 af[4], bfr[4];
        #pragma unroll
        for (int i = 0; i < 4; ++i)
            af[i] = *(const bf16x8*)&sA[buf][wr * 64 + i * 16 + lrow][kq * 8];
        #pragma unroll
        for (int n = 0; n < 4; ++n)
            bfr[n] = *(const bf16x8*)&sB[buf][wc * 64 + n * 16 + lrow][kq * 8];

        #pragma unroll
        for (int i = 0; i < 4; ++i)
            #pragma unroll
            for (int n = 0; n < 4; ++n)
                acc[i][n] = __builtin_amdgcn_mfma_f32_16x16x32_bf16(af[i], bfr[n], acc[i][n], 0, 0, 0);

        if (t + 1 < NT) WRITE((t + 1) & 1); // vmcnt drains here (loads had MFMA phase to land)
        __syncthreads();                     // one barrier per K-step (2 LDS buffers)
    }

    // Epilogue. C/D layout (m89-verified): col = lane&15, row = (lane>>4)*4 + reg
    const size_t crow0 = (size_t)e * TOKS;
    if constexpr (RELU_OUT_BF16) {
        unsigned short* C = (unsigned short*)Cp;
        #pragma unroll
        for (int i = 0; i < 4; ++i)
            #pragma unroll
            for (int n = 0; n < 4; ++n)
                #pragma unroll
                for (int q = 0; q < 4; ++q) {
                    const int row = wr * 64 + i * 16 + kq * 4 + q;
                    const int col = nt * 128 + wc * 64 + n * 16 + lrow;
                    C[(crow0 + row) * N + col] = f2bf(fmaxf(acc[i][n][q], 0.f));
                }
    } else {
        float* C = (float*)Cp;
        #pragma unroll
        for (int i = 0; i < 4; ++i)
            #pragma unroll
            for (int n = 0; n < 4; ++n)
                #pragma unroll
                for (int q = 0; q < 4; ++q) {
                    const int row = wr * 64 + i * 16 + kq * 4 + q;
                    const int col = nt * 128 + wc * 64 + n * 16 + lrow;
                    C[(crow0 + row) * N + col] = acc[i][n][q];
                }
    }
}

extern "C" void kernel_launch(void* const* d_in, const int* in_sizes, int n_in,
                              void* d_out, int out_size, void* d_ws, size_t ws_size,
                              hipStream_t stream) {
    const float* inputs = (const float*)d_in[0];   // [8192, 1024] fp32
    const float* w1     = (const float*)d_in[1];   // [64, 4096, 1024] fp32
    const float* w2     = (const float*)d_in[2];   // [64, 1024, 4096] fp32
    // d_in[3] = splits (always 128) -- unused

    unsigned short* h = (unsigned short*)d_ws;     // [8192, 4096] bf16 = 64 MiB
    float* out = (float*)d_out;                    // [8192, 1024] fp32

    // Pass 1: h = relu(x @ w1^T), bf16
    moe_gemm<DH, DM, false, true><<<dim3(N_EXPERTS * (DH / 128)), dim3(256), 0, stream>>>(
        inputs, w1, h);
    // Pass 2: out = h @ w2^T, fp32
    moe_gemm<DM, DH, true, false><<<dim3(N_EXPERTS * (DM / 128)), dim3(256), 0, stream>>>(
        h, w2, out);
}

// Round 2
// 615.492 us; speedup vs baseline: 1.0603x; 1.0603x over previous
//
#include <hip/hip_runtime.h>
#include <hip/hip_bf16.h>

// SeqExperts: 64 experts, 128 tokens each, d_model=1024, d_hidden=4096.
// out[e*128+m] = relu(x_e @ W1[e]^T) @ W2[e]^T
// Two grouped-GEMM passes, bf16 MFMA, weights converted fp32->bf16 at LDS-stage time.
// R2: + XCD-aware block swizzle (T1) so all N-tiles of an expert share one XCD's L2
//     -> A-operand (x in pass1, h in pass2) fetched from HBM once instead of up to 8x.

typedef __attribute__((ext_vector_type(8))) short bf16x8;   // 8 bf16 = 4 VGPRs (MFMA A/B frag)
typedef __attribute__((ext_vector_type(4))) float f32x4;    // MFMA C/D frag

#define N_EXPERTS 64
#define DM 1024
#define DH 4096
#define TOKS 128

// RNE fp32 -> bf16 (no NaN handling needed: inputs are finite normals)
__device__ __forceinline__ unsigned short f2bf(float f) {
    union { float f; unsigned u; } v; v.f = f;
    unsigned r = v.u + 0x7FFFu + ((v.u >> 16) & 1u);
    return (unsigned short)(r >> 16);
}

// C[128 x N] = A[128 x K] * B[N x K]^T  for expert e
// A: fp32 (pass1 inputs) or bf16 (pass2 h), row-major lda=K
// B: fp32 weights, row-major [N][K] (so B^T layout: K contiguous)
// C: pass1 -> bf16 + relu (h), pass2 -> fp32 (out). ldc=N.
template<int N, int K, bool A_BF16, bool RELU_OUT_BF16>
__global__ __launch_bounds__(256, 2)
void moe_gemm(const void* __restrict__ Ap, const float* __restrict__ Bp,
              void* __restrict__ Cp, int nwg_per_xcd)
{
    constexpr int BK = 32;          // K elements per LDS tile
    constexpr int NT = K / BK;      // K-steps
    constexpr int NTILES = N / 128; // N tiles per expert

    __shared__ unsigned short sA[2][128][BK];  // bf16 tiles, [buf][row][k] (8 KiB each)
    __shared__ unsigned short sB[2][128][BK];

    const int tid = threadIdx.x;
    // XCD-aware swizzle (grid % 8 == 0, bijective): dispatch-slot -> work-id such
    // that XCD x gets contiguous work ids [x*nwg_per_xcd, (x+1)*nwg_per_xcd).
    // Consecutive work ids = same expert -> A slab stays in that XCD's L2.
    const int bid = (blockIdx.x & 7) * nwg_per_xcd + (blockIdx.x >> 3);
    const int e   = bid / NTILES;
    const int nt  = bid % NTILES;

    const int lane = tid & 63;
    const int w    = tid >> 6;       // wave 0..3
    const int wr   = w >> 1;         // wave row (0..1) -> 64 rows
    const int wc   = w & 1;          // wave col (0..1) -> 64 cols
    const int lrow = lane & 15;      // fragment row/col index
    const int kq   = lane >> 4;      // k-quarter 0..3 (8 bf16 each)

    const float* Bbase = Bp + (size_t)e * N * K + (size_t)nt * 128 * K;

    const float*          Af = nullptr;
    const unsigned short* Ah = nullptr;
    if constexpr (A_BF16) Ah = (const unsigned short*)Ap + (size_t)e * TOKS * K;
    else                  Af = (const float*)Ap + (size_t)e * TOKS * K;

    // staging decomposition
    const int srow = tid >> 3;   // 0..31 (fp32 tiles: row = srow + j*32, 4 float4/row-group)
    const int sc4  = tid & 7;    // float4 column within row (cols sc4*4 .. +3)
    const int hrow = tid >> 2;   // 0..63 (bf16 A tile: row = hrow + j*64)
    const int hc8  = tid & 3;    // 8-bf16 chunk within row

    float4 bReg[4];
    float4 aRegF[4];
    uint4  aRegH[2];

    f32x4 acc[4][4];
    #pragma unroll
    for (int i = 0; i < 4; ++i)
        #pragma unroll
        for (int n = 0; n < 4; ++n)
            #pragma unroll
            for (int q = 0; q < 4; ++q) acc[i][n][q] = 0.f;

    auto LOAD = [&](int t) {
        const int k0 = t * BK;
        #pragma unroll
        for (int j = 0; j < 4; ++j)
            bReg[j] = *(const float4*)(Bbase + (size_t)(srow + j * 32) * K + k0 + sc4 * 4);
        if constexpr (A_BF16) {
            #pragma unroll
            for (int j = 0; j < 2; ++j)
                aRegH[j] = *(const uint4*)(Ah + (size_t)(hrow + j * 64) * K + k0 + hc8 * 8);
        } else {
            #pragma unroll
            for (int j = 0; j < 4; ++j)
                aRegF[j] = *(const float4*)(Af + (size_t)(srow + j * 32) * K + k0 + sc4 * 4);
        }
    };

    auto WRITE = [&](int buf) {
        #pragma unroll
        for (int j = 0; j < 4; ++j) {
            ushort4 p;
            p.x = f2bf(bReg[j].x); p.y = f2bf(bReg[j].y);
            p.z = f2bf(bReg[j].z); p.w = f2bf(bReg[j].w);
            *(ushort4*)&sB[buf][srow + j * 32][sc4 * 4] = p;
        }
        if constexpr (A_BF16) {
            #pragma unroll
            for (int j = 0; j < 2; ++j)
                *(uint4*)&sA[buf][hrow + j * 64][hc8 * 8] = aRegH[j];
        } else {
            #pragma unroll
            for (int j = 0; j < 4; ++j) {
                ushort4 p;
                p.x = f2bf(aRegF[j].x); p.y = f2bf(aRegF[j].y);
                p.z = f2bf(aRegF[j].z); p.w = f2bf(aRegF[j].w);
                *(ushort4*)&sA[buf][srow + j * 32][sc4 * 4] = p;
            }
        }
    };

    LOAD(0);
    WRITE(0);
    __syncthreads();

    #pragma unroll 2
    for (int t = 0; t < NT; ++t) {
        const int buf = t & 1;
        if (t + 1 < NT) LOAD(t + 1);       // issue next tile's global loads early

        bf16x8 af[4], bfr[4];
        #pragma unroll
        for (int i = 0; i < 4; ++i)
            af[i] = *(const bf16x8*)&sA[buf][wr * 64 + i * 16 + lrow][kq * 8];
        #pragma unroll
        for (int n = 0; n < 4; ++n)
            bfr[n] = *(const bf16x8*)&sB[buf][wc * 64 + n * 16 + lrow][kq * 8];

        #pragma unroll
        for (int i = 0; i < 4; ++i)
            #pragma unroll
            for (int n = 0; n < 4; ++n)
                acc[i][n] = __builtin_amdgcn_mfma_f32_16x16x32_bf16(af[i], bfr[n], acc[i][n], 0, 0, 0);

        if (t + 1 < NT) WRITE((t + 1) & 1); // vmcnt drains here (loads had MFMA phase to land)
        __syncthreads();                     // one barrier per K-step (2 LDS buffers)
    }

    // Epilogue. C/D layout (m89-verified): col = lane&15, row = (lane>>4)*4 + reg
    const size_t crow0 = (size_t)e * TOKS;
    if constexpr (RELU_OUT_BF16) {
        unsigned short* C = (unsigned short*)Cp;
        #pragma unroll
        for (int i = 0; i < 4; ++i)
            #pragma unroll
            for (int n = 0; n < 4; ++n)
                #pragma unroll
                for (int q = 0; q < 4; ++q) {
                    const int row = wr * 64 + i * 16 + kq * 4 + q;
                    const int col = nt * 128 + wc * 64 + n * 16 + lrow;
                    C[(crow0 + row) * N + col] = f2bf(fmaxf(acc[i][n][q], 0.f));
                }
    } else {
        float* C = (float*)Cp;
        #pragma unroll
        for (int i = 0; i < 4; ++i)
            #pragma unroll
            for (int n = 0; n < 4; ++n)
                #pragma unroll
                for (int q = 0; q < 4; ++q) {
                    const int row = wr * 64 + i * 16 + kq * 4 + q;
                    const int col = nt * 128 + wc * 64 + n * 16 + lrow;
                    C[(crow0 + row) * N + col] = acc[i][n][q];
                }
    }
}

extern "C" void kernel_launch(void* const* d_in, const int* in_sizes, int n_in,
                              void* d_out, int out_size, void* d_ws, size_t ws_size,
                              hipStream_t stream) {
    const float* inputs = (const float*)d_in[0];   // [8192, 1024] fp32
    const float* w1     = (const float*)d_in[1];   // [64, 4096, 1024] fp32
    const float* w2     = (const float*)d_in[2];   // [64, 1024, 4096] fp32
    // d_in[3] = splits (always 128) -- unused

    unsigned short* h = (unsigned short*)d_ws;     // [8192, 4096] bf16 = 64 MiB
    float* out = (float*)d_out;                    // [8192, 1024] fp32

    // Pass 1: h = relu(x @ w1^T), bf16. grid = 64*32 = 2048 (divisible by 8)
    moe_gemm<DH, DM, false, true><<<dim3(N_EXPERTS * (DH / 128)), dim3(256), 0, stream>>>(
        inputs, w1, h, N_EXPERTS * (DH / 128) / 8);
    // Pass 2: out = h @ w2^T, fp32. grid = 64*8 = 512 (divisible by 8)
    moe_gemm<DM, DH, true, false><<<dim3(N_EXPERTS * (DM / 128)), dim3(256), 0, stream>>>(
        h, w2, out, N_EXPERTS * (DM / 128) / 8);
}

// Round 3
// 539.637 us; speedup vs baseline: 1.2093x; 1.1406x over previous
//
#include <hip/hip_runtime.h>
#include <hip/hip_bf16.h>

// SeqExperts: 64 experts, 128 tokens each, d_model=1024, d_hidden=4096.
// out[e*128+m] = relu(x_e @ W1[e]^T) @ W2[e]^T
// Two grouped-GEMM passes, bf16 MFMA, weights converted fp32->bf16 at LDS-stage time.
// R2: XCD-aware block swizzle (T1).
// R3: 2-deep register prefetch + raw s_barrier with counted vmcnt (T3/T4-lite):
//     never drain the HBM queue to zero inside the K-loop. Two NAMED reg sets
//     (static indexing, rule #20); compiler auto-emits vmcnt(8) at WRITE since
//     the 8 newer loads are register-disjoint.

typedef __attribute__((ext_vector_type(8))) short bf16x8;   // 8 bf16 = 4 VGPRs (MFMA A/B frag)
typedef __attribute__((ext_vector_type(4))) float f32x4;    // MFMA C/D frag

#define N_EXPERTS 64
#define DM 1024
#define DH 4096
#define TOKS 128

// RNE fp32 -> bf16 (no NaN handling needed: inputs are finite normals)
__device__ __forceinline__ unsigned short f2bf(float f) {
    union { float f; unsigned u; } v; v.f = f;
    unsigned r = v.u + 0x7FFFu + ((v.u >> 16) & 1u);
    return (unsigned short)(r >> 16);
}

// C[128 x N] = A[128 x K] * B[N x K]^T  for expert e
template<int N, int K, bool A_BF16, bool RELU_OUT_BF16>
__global__ __launch_bounds__(256, 2)
void moe_gemm(const void* __restrict__ Ap, const float* __restrict__ Bp,
              void* __restrict__ Cp, int nwg_per_xcd)
{
    constexpr int BK = 32;          // K elements per LDS tile
    constexpr int NT = K / BK;      // K-steps (32 or 128; both even)
    constexpr int NTILES = N / 128; // N tiles per expert

    __shared__ unsigned short sA[2][128][BK];  // bf16 tiles [buf][row][k] (8 KiB each)
    __shared__ unsigned short sB[2][128][BK];

    const int tid = threadIdx.x;
    // XCD-aware swizzle (grid % 8 == 0, bijective)
    const int bid = (blockIdx.x & 7) * nwg_per_xcd + (blockIdx.x >> 3);
    const int e   = bid / NTILES;
    const int nt  = bid % NTILES;

    const int lane = tid & 63;
    const int w    = tid >> 6;       // wave 0..3
    const int wr   = w >> 1;         // wave row (0..1) -> 64 rows
    const int wc   = w & 1;          // wave col (0..1) -> 64 cols
    const int lrow = lane & 15;
    const int kq   = lane >> 4;      // k-quarter 0..3 (8 bf16 each)

    const float* Bbase = Bp + (size_t)e * N * K + (size_t)nt * 128 * K;

    const float*          Af = nullptr;
    const unsigned short* Ah = nullptr;
    if constexpr (A_BF16) Ah = (const unsigned short*)Ap + (size_t)e * TOKS * K;
    else                  Af = (const float*)Ap + (size_t)e * TOKS * K;

    const int srow = tid >> 3;   // 0..31 (fp32 staging: rows srow + j*32)
    const int sc4  = tid & 7;    // float4 column
    const int hrow = tid >> 2;   // 0..63 (bf16 A staging)
    const int hc8  = tid & 3;

    struct Regs {
        float4 b[4];
        float4 af[4];   // only live when !A_BF16 (DCE'd otherwise)
        uint4  ah[2];   // only live when A_BF16
    };
    Regs r0, r1;

    f32x4 acc[4][4];
    #pragma unroll
    for (int i = 0; i < 4; ++i)
        #pragma unroll
        for (int n = 0; n < 4; ++n)
            #pragma unroll
            for (int q = 0; q < 4; ++q) acc[i][n][q] = 0.f;

    auto LOAD = [&](int t, Regs& r) {
        const int k0 = t * BK;
        #pragma unroll
        for (int j = 0; j < 4; ++j)
            r.b[j] = *(const float4*)(Bbase + (size_t)(srow + j * 32) * K + k0 + sc4 * 4);
        if constexpr (A_BF16) {
            #pragma unroll
            for (int j = 0; j < 2; ++j)
                r.ah[j] = *(const uint4*)(Ah + (size_t)(hrow + j * 64) * K + k0 + hc8 * 8);
        } else {
            #pragma unroll
            for (int j = 0; j < 4; ++j)
                r.af[j] = *(const float4*)(Af + (size_t)(srow + j * 32) * K + k0 + sc4 * 4);
        }
    };

    auto WRITE = [&](int buf, Regs& r) {
        #pragma unroll
        for (int j = 0; j < 4; ++j) {
            ushort4 p;
            p.x = f2bf(r.b[j].x); p.y = f2bf(r.b[j].y);
            p.z = f2bf(r.b[j].z); p.w = f2bf(r.b[j].w);
            *(ushort4*)&sB[buf][srow + j * 32][sc4 * 4] = p;
        }
        if constexpr (A_BF16) {
            #pragma unroll
            for (int j = 0; j < 2; ++j)
                *(uint4*)&sA[buf][hrow + j * 64][hc8 * 8] = r.ah[j];
        } else {
            #pragma unroll
            for (int j = 0; j < 4; ++j) {
                ushort4 p;
                p.x = f2bf(r.af[j].x); p.y = f2bf(r.af[j].y);
                p.z = f2bf(r.af[j].z); p.w = f2bf(r.af[j].w);
                *(ushort4*)&sA[buf][srow + j * 32][sc4 * 4] = p;
            }
        }
    };

    auto COMPUTE = [&](int buf) {
        bf16x8 af[4], bfr[4];
        #pragma unroll
        for (int i = 0; i < 4; ++i)
            af[i] = *(const bf16x8*)&sA[buf][wr * 64 + i * 16 + lrow][kq * 8];
        #pragma unroll
        for (int n = 0; n < 4; ++n)
            bfr[n] = *(const bf16x8*)&sB[buf][wc * 64 + n * 16 + lrow][kq * 8];
        #pragma unroll
        for (int i = 0; i < 4; ++i)
            #pragma unroll
            for (int n = 0; n < 4; ++n)
                acc[i][n] = __builtin_amdgcn_mfma_f32_16x16x32_bf16(af[i], bfr[n], acc[i][n], 0, 0, 0);
    };

    // Prologue: 2 tiles in flight before first barrier.
    LOAD(0, r0);
    LOAD(1, r1);
    WRITE(0, r0);                         // compiler waits only r0's loads (vmcnt counted)
    asm volatile("s_waitcnt lgkmcnt(0)" ::: "memory");
    __builtin_amdgcn_s_barrier();

    for (int t = 0; t < NT; t += 2) {
        // even sub-iter u = t: load t+2 -> r0, compute buf0, write tile t+1 (r1) -> buf1
        if (t + 2 < NT) LOAD(t + 2, r0);
        COMPUTE(0);
        if (t + 1 < NT) WRITE(1, r1);     // auto vmcnt(~8): r0's newer loads stay in flight
        asm volatile("s_waitcnt lgkmcnt(0)" ::: "memory");
        __builtin_amdgcn_s_barrier();

        // odd sub-iter u = t+1: load t+3 -> r1, compute buf1, write tile t+2 (r0) -> buf0
        if (t + 3 < NT) LOAD(t + 3, r1);
        COMPUTE(1);
        if (t + 2 < NT) WRITE(0, r0);
        asm volatile("s_waitcnt lgkmcnt(0)" ::: "memory");
        __builtin_amdgcn_s_barrier();
    }

    // Epilogue. C/D layout (m89-verified): col = lane&15, row = (lane>>4)*4 + reg
    const size_t crow0 = (size_t)e * TOKS;
    if constexpr (RELU_OUT_BF16) {
        unsigned short* C = (unsigned short*)Cp;
        #pragma unroll
        for (int i = 0; i < 4; ++i)
            #pragma unroll
            for (int n = 0; n < 4; ++n)
                #pragma unroll
                for (int q = 0; q < 4; ++q) {
                    const int row = wr * 64 + i * 16 + kq * 4 + q;
                    const int col = nt * 128 + wc * 64 + n * 16 + lrow;
                    C[(crow0 + row) * N + col] = f2bf(fmaxf(acc[i][n][q], 0.f));
                }
    } else {
        float* C = (float*)Cp;
        #pragma unroll
        for (int i = 0; i < 4; ++i)
            #pragma unroll
            for (int n = 0; n < 4; ++n)
                #pragma unroll
                for (int q = 0; q < 4; ++q) {
                    const int row = wr * 64 + i * 16 + kq * 4 + q;
                    const int col = nt * 128 + wc * 64 + n * 16 + lrow;
                    C[(crow0 + row) * N + col] = acc[i][n][q];
                }
    }
}

extern "C" void kernel_launch(void* const* d_in, const int* in_sizes, int n_in,
                              void* d_out, int out_size, void* d_ws, size_t ws_size,
                              hipStream_t stream) {
    const float* inputs = (const float*)d_in[0];   // [8192, 1024] fp32
    const float* w1     = (const float*)d_in[1];   // [64, 4096, 1024] fp32
    const float* w2     = (const float*)d_in[2];   // [64, 1024, 4096] fp32
    // d_in[3] = splits (always 128) -- unused

    unsigned short* h = (unsigned short*)d_ws;     // [8192, 4096] bf16 = 64 MiB
    float* out = (float*)d_out;                    // [8192, 1024] fp32

    // Pass 1: h = relu(x @ w1^T), bf16. grid = 64*32 = 2048
    moe_gemm<DH, DM, false, true><<<dim3(N_EXPERTS * (DH / 128)), dim3(256), 0, stream>>>(
        inputs, w1, h, N_EXPERTS * (DH / 128) / 8);
    // Pass 2: out = h @ w2^T, fp32. grid = 64*8 = 512
    moe_gemm<DM, DH, true, false><<<dim3(N_EXPERTS * (DM / 128)), dim3(256), 0, stream>>>(
        h, w2, out, N_EXPERTS * (DM / 128) / 8);
}